// Round 13
// baseline (219.911 us; speedup 1.0000x reference)
//
#include <hip/hip_runtime.h>
#include <hip/hip_fp16.h>
#include <math.h>

#define T_TOKENS 16384
#define D_DIM    2048
#define NEXP     256
#define TOPK     8
#define NLIM     4
#define BM       16          // 16 tokens/block -> grid 1024 -> 4 blocks/CU
#define NSS      16          // supersteps, BK=128 each (4 sub-k of 32)
#define NTHREADS 512         // 8 waves -> 32 waves/CU (8/SIMD)

typedef __attribute__((ext_vector_type(8))) _Float16 f16x8;  // 4 VGPRs
typedef __attribute__((ext_vector_type(4))) float f32x4;     // MFMA acc

typedef __attribute__((address_space(1))) const float g_float;
typedef __attribute__((address_space(3))) float l_float;

// LDS: A = raw f32 x-fragments, 3-ring (8 KB/ring); Sc aliases after GEMM.
//  A[ring][ks(4)][jh(2)][lane(64)][4 f32]
struct GemmBufs { float A[3][4][2][64][4]; };      // 24 KB
union SMem {
  GemmBufs g;
  float Sc[BM][260];                               // 16.6 KB
};
// sizeof(SMem)=24KB; +hist 1KB -> ~25KB/block -> 4 blocks/CU resident

// ---- pre-pass: w[256][2048] f32 -> fp16 in MFMA-fragment order ----
// wf layout (fp16): [ks(64)][nfg(16)][lane(64)][j(8)]
// value = (half) w[ e = nfg*16 + (lane&15) ][ k = ks*32 + (lane>>4)*8 + j ]
__global__ __launch_bounds__(256) void prep_w(const float* __restrict__ w,
                                              unsigned short* __restrict__ wf) {
  const int g   = blockIdx.x * 256 + threadIdx.x;  // 0..65535
  const int ks  = g >> 10;
  const int rem = g & 1023;
  const int nfg = rem >> 6;
  const int l   = rem & 63;
  const int e   = nfg * 16 + (l & 15);
  const int kb  = ks * 32 + ((l >> 4) << 3);
  const float* src = &w[(size_t)e * D_DIM + kb];
  float f[8];
  *reinterpret_cast<float4*>(&f[0]) = *reinterpret_cast<const float4*>(src);
  *reinterpret_cast<float4*>(&f[4]) = *reinterpret_cast<const float4*>(src + 4);
  union { unsigned short s[8]; float4 v; } h;
  #pragma unroll
  for (int j = 0; j < 8; ++j) h.s[j] = __half_as_ushort(__float2half(f[j]));
  *reinterpret_cast<float4*>(wf + (size_t)ks * 8192 + nfg * 512 + l * 8) = h.v;
}

__device__ __forceinline__ unsigned cvt2(float a, float b) {  // RNE
  return (unsigned)__half_as_ushort(__float2half(a)) |
         ((unsigned)__half_as_ushort(__float2half(b)) << 16);
}
__device__ __forceinline__ f16x8 cvt8(const float4& lo, const float4& hi) {
  union { unsigned u[4]; f16x8 v; } h;
  h.u[0] = cvt2(lo.x, lo.y); h.u[1] = cvt2(lo.z, lo.w);
  h.u[2] = cvt2(hi.x, hi.y); h.u[3] = cvt2(hi.z, hi.w);
  return h.v;
}

// ---- fused GEMM (fp16 MFMA; A via 3-ring gll-LDS; B in registers) ----
__global__ __launch_bounds__(NTHREADS, 8) void gate_kernel(
    const float* __restrict__ x,
    const unsigned short* __restrict__ wf,
    const float* __restrict__ bias,
    float* __restrict__ out_w,
    float* __restrict__ out_idx,
    float* __restrict__ out_load) {

  __shared__ SMem sm;
  __shared__ int hist[NEXP];

  const int tid  = threadIdx.x;
  const int row0 = blockIdx.x * BM;
  const int lane = tid & 63;
  const int wid  = tid >> 6;   // 0..7 ; wave owns experts wid*32..wid*32+31

  for (int i = tid; i < NEXP; i += NTHREADS) hist[i] = 0;

  // gll lane-source base for A: row = row0 + (lane&15), k-base = (lane>>4)*8
  const float* xsrc =
      &x[(size_t)(row0 + (lane & 15)) * D_DIM + ((lane >> 4) << 3)];
  // this wave's single chunk: c = wid -> (ks = c>>1, jh = c&1)
  const int ksw = wid >> 1, jhw = wid & 1;
  const float* s0 = xsrc + ksw * 32 + jhw * 4;
  // B source base (fragment-linear wf)
  const unsigned short* wfB = wf + (size_t)(wid * 2) * 512 + (size_t)lane * 8;

  f32x4 acc[2];
  acc[0] = (f32x4)(0.0f);
  acc[1] = (f32x4)(0.0f);

  // ---- prologue: stage supersteps 0 and 1 into rings 0,1 (1 gll each)
  __builtin_amdgcn_global_load_lds((g_float*)(s0),
      (l_float*)&sm.g.A[0][ksw][jhw][0][0], 16, 0, 0);
  __builtin_amdgcn_global_load_lds((g_float*)(s0 + 128),
      (l_float*)&sm.g.A[1][ksw][jhw][0][0], 16, 0, 0);
  asm volatile("s_waitcnt vmcnt(1)" ::: "memory");  // ring0 landed; ring1 flies
  __builtin_amdgcn_sched_barrier(0);
  __builtin_amdgcn_s_barrier();
  __builtin_amdgcn_sched_barrier(0);

  // ---- 16 supersteps; ONE barrier each.
  // gll(n+2) is older than B(n+1) reg-loads, so the compiler's B-register
  // wait before MFMA(n+1) retires gll(n+2) before barrier(n+1) -> the ring
  // written by gll(n+2) is visible to all waves at superstep n+2.
  for (int n = 0; n < NSS; ++n) {
    const int ring = n % 3;
    // (1) B(n): 8 dwordx4 into regs (wave-private, L2-hot)
    f16x8 b[2][4];
    #pragma unroll
    for (int nf = 0; nf < 2; ++nf)
      #pragma unroll
      for (int ks = 0; ks < 4; ++ks)
        b[nf][ks] = *reinterpret_cast<const f16x8*>(
            wfB + (size_t)(n * 4 + ks) * 8192 + nf * 512);
    // (2) A(n): 4 fragments from LDS ring, cvt f32->fp16 (RNE)
    f16x8 a[4];
    #pragma unroll
    for (int ks = 0; ks < 4; ++ks) {
      float4 lo = *reinterpret_cast<const float4*>(&sm.g.A[ring][ks][0][lane][0]);
      float4 hi = *reinterpret_cast<const float4*>(&sm.g.A[ring][ks][1][lane][0]);
      a[ks] = cvt8(lo, hi);
    }
    __builtin_amdgcn_sched_barrier(0);
    // (3) stage A(n+2) into ring (n+2)%3 (this wave's 1 KB chunk)
    if (n + 2 < NSS) {
      __builtin_amdgcn_global_load_lds((g_float*)(s0 + (n + 2) * 128),
          (l_float*)&sm.g.A[(n + 2) % 3][ksw][jhw][0][0], 16, 0, 0);
    }
    __builtin_amdgcn_sched_barrier(0);
    // (4) 8 MFMA
    #pragma unroll
    for (int ks = 0; ks < 4; ++ks) {
      acc[0] = __builtin_amdgcn_mfma_f32_16x16x32_f16(a[ks], b[0][ks], acc[0], 0, 0, 0);
      acc[1] = __builtin_amdgcn_mfma_f32_16x16x32_f16(a[ks], b[1][ks], acc[1], 0, 0, 0);
    }
    // (5) barrier: ring(n+1) safe to read next iter
    __builtin_amdgcn_sched_barrier(0);
    __builtin_amdgcn_s_barrier();
    __builtin_amdgcn_sched_barrier(0);
  }
  __syncthreads();   // full drain; safe to alias Sc over A

  // ---- epilogue: logits -> Sc (C/D layout: col=lane&15, row=(lane>>4)*4+r)
  #pragma unroll
  for (int nf = 0; nf < 2; ++nf)
    #pragma unroll
    for (int r = 0; r < 4; ++r) {
      const int row = ((lane >> 4) << 2) + r;
      const int col = wid * 32 + nf * 16 + (lane & 15);
      sm.Sc[row][col] = acc[nf][r];
    }
  __syncthreads();

  // ---- routing: one wave per token, lane holds experts 4l..4l+3
  const float4 bsl = *reinterpret_cast<const float4*>(&bias[lane * 4]);
  const int g = lane >> 3;   // group of this lane's experts

  for (int m = wid; m < BM; m += 8) {
    float v[4];
    *reinterpret_cast<float4*>(v) =
        *reinterpret_cast<const float4*>(&sm.Sc[m][lane * 4]);

    // softmax (match jax: subtract row max, exp, divide by sum)
    float mx = fmaxf(fmaxf(v[0], v[1]), fmaxf(v[2], v[3]));
    #pragma unroll
    for (int s = 1; s < 64; s <<= 1) mx = fmaxf(mx, __shfl_xor(mx, s));
    float ex[4], sum = 0.f;
    #pragma unroll
    for (int j = 0; j < 4; ++j) { ex[j] = expf(v[j] - mx); sum += ex[j]; }
    #pragma unroll
    for (int s = 1; s < 64; s <<= 1) sum += __shfl_xor(sum, s);
    float sc[4], sel[4];
    sc[0] = ex[0] / sum; sc[1] = ex[1] / sum;
    sc[2] = ex[2] / sum; sc[3] = ex[3] / sum;
    sel[0] = sc[0] + bsl.x; sel[1] = sc[1] + bsl.y;
    sel[2] = sc[2] + bsl.z; sel[3] = sc[3] + bsl.w;

    // keep original scores for the gather
    *reinterpret_cast<float4*>(&sm.Sc[m][lane * 4]) =
        make_float4(sc[0], sc[1], sc[2], sc[3]);

    // group max (groups of 32 experts = 8 lanes)
    float gv = fmaxf(fmaxf(sel[0], sel[1]), fmaxf(sel[2], sel[3]));
    gv = fmaxf(gv, __shfl_xor(gv, 1));
    gv = fmaxf(gv, __shfl_xor(gv, 2));
    gv = fmaxf(gv, __shfl_xor(gv, 4));

    // top-4 groups, tie -> lower group index (jax.lax.top_k stability)
    unsigned gmask = 0;
    float gcur = gv;
    #pragma unroll
    for (int it = 0; it < NLIM; ++it) {
      float bv2 = gcur; int bi = g;
      #pragma unroll
      for (int s = 1; s < 64; s <<= 1) {
        float ov = __shfl_xor(bv2, s);
        int   oi = __shfl_xor(bi, s);
        if (ov > bv2 || (ov == bv2 && oi < bi)) { bv2 = ov; bi = oi; }
      }
      gmask |= 1u << bi;
      if (g == bi) gcur = -INFINITY;
    }
    if (!((gmask >> g) & 1u)) {
      sel[0] = sel[1] = sel[2] = sel[3] = -INFINITY;
    }

    // top-8 experts, tie -> lower expert index
    const int gtok = row0 + m;
    #pragma unroll
    for (int it = 0; it < TOPK; ++it) {
      float bv2 = sel[0]; int bi = lane * 4;
      #pragma unroll
      for (int j = 1; j < 4; ++j)
        if (sel[j] > bv2) { bv2 = sel[j]; bi = lane * 4 + j; }
      #pragma unroll
      for (int s = 1; s < 64; s <<= 1) {
        float ov = __shfl_xor(bv2, s);
        int   oi = __shfl_xor(bi, s);
        if (ov > bv2 || (ov == bv2 && oi < bi)) { bv2 = ov; bi = oi; }
      }
      if (lane == 0) {
        out_w[(size_t)gtok * TOPK + it]   = sm.Sc[m][bi] * 2.5f;
        out_idx[(size_t)gtok * TOPK + it] = (float)bi;
        atomicAdd(&hist[bi], 1);
      }
      if ((bi >> 2) == lane) sel[bi & 3] = -INFINITY;
    }
  }

  __syncthreads();
  for (int b = tid; b < NEXP; b += NTHREADS)
    if (hist[b]) atomicAdd(&out_load[b], (float)hist[b]);
}

extern "C" void kernel_launch(void* const* d_in, const int* in_sizes, int n_in,
                              void* d_out, int out_size, void* d_ws, size_t ws_size,
                              hipStream_t stream) {
  const float* x    = (const float*)d_in[0];
  const float* w    = (const float*)d_in[1];
  const float* bias = (const float*)d_in[2];
  float* out_w    = (float*)d_out;
  float* out_idx  = out_w + (size_t)T_TOKENS * TOPK;
  float* out_load = out_idx + (size_t)T_TOKENS * TOPK;
  unsigned short* wfrag = (unsigned short*)d_ws;   // 1 MB fragment-ordered fp16 w

  hipMemsetAsync(out_load, 0, NEXP * sizeof(float), stream);
  prep_w<<<256, 256, 0, stream>>>(w, wfrag);
  gate_kernel<<<T_TOKENS / BM, NTHREADS, 0, stream>>>(
      x, wfrag, bias, out_w, out_idx, out_load);
}

// Round 14
// 178.001 us; speedup vs baseline: 1.2354x; 1.2354x over previous
//
#include <hip/hip_runtime.h>
#include <hip/hip_fp16.h>
#include <math.h>

#define T_TOKENS 16384
#define D_DIM    2048
#define NEXP     256
#define TOPK     8
#define NLIM     4
#define BM       16          // block tile: 16 tokens; grid 1024 = 4 blocks/CU
#define KSTEPS   (D_DIM / 32)  // 64 k-steps of 32
#define NTHREADS 512         // 8 waves; each wave: 16 tok x 32 experts

typedef __attribute__((ext_vector_type(8))) _Float16 f16x8;  // 4 VGPRs
typedef __attribute__((ext_vector_type(4))) float f32x4;     // MFMA acc

// ---- pre-pass: w[256][2048] f32 -> fp16 in MFMA-fragment order ----
// wf layout (fp16): [ks(64)][nfg(16)][lane(64)][j(8)]
// value = (half) w[ e = nfg*16 + (lane&15) ][ k = ks*32 + (lane>>4)*8 + j ]
__global__ __launch_bounds__(256) void prep_w(const float* __restrict__ w,
                                              unsigned short* __restrict__ wf) {
  const int g   = blockIdx.x * 256 + threadIdx.x;  // 0..65535
  const int ks  = g >> 10;
  const int rem = g & 1023;
  const int nfg = rem >> 6;
  const int l   = rem & 63;
  const int e   = nfg * 16 + (l & 15);
  const int kb  = ks * 32 + ((l >> 4) << 3);
  const float* src = &w[(size_t)e * D_DIM + kb];
  float f[8];
  *reinterpret_cast<float4*>(&f[0]) = *reinterpret_cast<const float4*>(src);
  *reinterpret_cast<float4*>(&f[4]) = *reinterpret_cast<const float4*>(src + 4);
  union { unsigned short s[8]; float4 v; } h;
  #pragma unroll
  for (int j = 0; j < 8; ++j) h.s[j] = __half_as_ushort(__float2half(f[j]));
  *reinterpret_cast<float4*>(wf + (size_t)ks * 8192 + nfg * 512 + l * 8) = h.v;
}

__device__ __forceinline__ unsigned cvt2(float a, float b) {  // RNE
  return (unsigned)__half_as_ushort(__float2half(a)) |
         ((unsigned)__half_as_ushort(__float2half(b)) << 16);
}
__device__ __forceinline__ f16x8 cvt8(const float4& lo, const float4& hi) {
  union { unsigned u[4]; f16x8 v; } h;
  h.u[0] = cvt2(lo.x, lo.y); h.u[1] = cvt2(lo.z, lo.w);
  h.u[2] = cvt2(hi.x, hi.y); h.u[3] = cvt2(hi.z, hi.w);
  return h.v;
}

// ---- one K-step: issue loads for step t+1 into (na,nb); compute step t ----
// Register deps only. Live set ~54 VGPR < the 64-VGPR cap of (512,8):
// ca/na 16, cb/nb 16, acc 8, addresses ~10, temps ~4.
__device__ __forceinline__ void kstep(
    int t, const float* xp, const unsigned short* wfB,
    float4 (&ca)[2], f16x8 (&cb)[2],
    float4 (&na)[2], f16x8 (&nb)[2],
    f32x4 (&acc)[2]) {
  const int kn = (t + 1 < KSTEPS) ? t + 1 : KSTEPS - 1;
  na[0] = *reinterpret_cast<const float4*>(xp + kn * 32);
  na[1] = *reinterpret_cast<const float4*>(xp + kn * 32 + 4);
  nb[0] = *reinterpret_cast<const f16x8*>(wfB + (size_t)kn * 8192);
  nb[1] = *reinterpret_cast<const f16x8*>(wfB + (size_t)kn * 8192 + 512);
  __builtin_amdgcn_sched_barrier(0);
  f16x8 a = cvt8(ca[0], ca[1]);
  acc[0] = __builtin_amdgcn_mfma_f32_16x16x32_f16(a, cb[0], acc[0], 0, 0, 0);
  acc[1] = __builtin_amdgcn_mfma_f32_16x16x32_f16(a, cb[1], acc[1], 0, 0, 0);
}

// ---- fused GEMM: barrier-free, LDS-free K-loop; 32 waves/CU of pure TLP ---
__global__ __launch_bounds__(NTHREADS, 8) void gate_kernel(
    const float* __restrict__ x,
    const unsigned short* __restrict__ wf,
    const float* __restrict__ bias,
    float* __restrict__ out_w,
    float* __restrict__ out_idx,
    float* __restrict__ out_load) {

  __shared__ float Sc[BM][260];   // scores for routing (+pad)
  __shared__ int hist[NEXP];

  const int tid  = threadIdx.x;
  const int row0 = blockIdx.x * BM;
  const int lane = tid & 63;
  const int wid  = tid >> 6;   // 0..7 ; wave owns experts wid*32..wid*32+31

  for (int i = tid; i < NEXP; i += NTHREADS) hist[i] = 0;

  // per-lane A source: row = row0 + (lane&15), k = t*32 + (lane>>4)*8 + j
  const float* xp =
      &x[(size_t)(row0 + (lane & 15)) * D_DIM + ((lane >> 4) << 3)];
  // per-lane B source (fragment-linear wf)
  const unsigned short* wfB = wf + (size_t)(wid * 2) * 512 + (size_t)lane * 8;

  f32x4 acc[2];
  acc[0] = (f32x4)(0.0f);
  acc[1] = (f32x4)(0.0f);

  float4 aA[2], aB[2];
  f16x8 bA[2], bB[2];

  // prologue: load step 0
  aA[0] = *reinterpret_cast<const float4*>(xp);
  aA[1] = *reinterpret_cast<const float4*>(xp + 4);
  bA[0] = *reinterpret_cast<const f16x8*>(wfB);
  bA[1] = *reinterpret_cast<const f16x8*>(wfB + 512);

  for (int t = 0; t < KSTEPS; t += 2) {
    kstep(t,     xp, wfB, aA, bA, aB, bB, acc);
    kstep(t + 1, xp, wfB, aB, bB, aA, bA, acc);
  }

  // ---- epilogue: logits -> Sc (C/D layout: col=lane&15, row=(lane>>4)*4+r)
  #pragma unroll
  for (int nf = 0; nf < 2; ++nf)
    #pragma unroll
    for (int r = 0; r < 4; ++r) {
      const int row = ((lane >> 4) << 2) + r;
      const int col = wid * 32 + nf * 16 + (lane & 15);
      Sc[row][col] = acc[nf][r];
    }
  __syncthreads();   // first and only pre-routing barrier

  // ---- routing: one wave per token, lane holds experts 4l..4l+3
  const float4 bsl = *reinterpret_cast<const float4*>(&bias[lane * 4]);
  const int g = lane >> 3;   // group of this lane's experts

  for (int m = wid; m < BM; m += 8) {
    float v[4];
    *reinterpret_cast<float4*>(v) =
        *reinterpret_cast<const float4*>(&Sc[m][lane * 4]);

    // softmax (match jax: subtract row max, exp, divide by sum)
    float mx = fmaxf(fmaxf(v[0], v[1]), fmaxf(v[2], v[3]));
    #pragma unroll
    for (int s = 1; s < 64; s <<= 1) mx = fmaxf(mx, __shfl_xor(mx, s));
    float ex[4], sum = 0.f;
    #pragma unroll
    for (int j = 0; j < 4; ++j) { ex[j] = expf(v[j] - mx); sum += ex[j]; }
    #pragma unroll
    for (int s = 1; s < 64; s <<= 1) sum += __shfl_xor(sum, s);
    float sc[4], sel[4];
    sc[0] = ex[0] / sum; sc[1] = ex[1] / sum;
    sc[2] = ex[2] / sum; sc[3] = ex[3] / sum;
    sel[0] = sc[0] + bsl.x; sel[1] = sc[1] + bsl.y;
    sel[2] = sc[2] + bsl.z; sel[3] = sc[3] + bsl.w;

    // keep original scores for the gather
    *reinterpret_cast<float4*>(&Sc[m][lane * 4]) =
        make_float4(sc[0], sc[1], sc[2], sc[3]);

    // group max (groups of 32 experts = 8 lanes)
    float gv = fmaxf(fmaxf(sel[0], sel[1]), fmaxf(sel[2], sel[3]));
    gv = fmaxf(gv, __shfl_xor(gv, 1));
    gv = fmaxf(gv, __shfl_xor(gv, 2));
    gv = fmaxf(gv, __shfl_xor(gv, 4));

    // top-4 groups, tie -> lower group index (jax.lax.top_k stability)
    unsigned gmask = 0;
    float gcur = gv;
    #pragma unroll
    for (int it = 0; it < NLIM; ++it) {
      float bv2 = gcur; int bi = g;
      #pragma unroll
      for (int s = 1; s < 64; s <<= 1) {
        float ov = __shfl_xor(bv2, s);
        int   oi = __shfl_xor(bi, s);
        if (ov > bv2 || (ov == bv2 && oi < bi)) { bv2 = ov; bi = oi; }
      }
      gmask |= 1u << bi;
      if (g == bi) gcur = -INFINITY;
    }
    if (!((gmask >> g) & 1u)) {
      sel[0] = sel[1] = sel[2] = sel[3] = -INFINITY;
    }

    // top-8 experts, tie -> lower expert index
    const int gtok = row0 + m;
    #pragma unroll
    for (int it = 0; it < TOPK; ++it) {
      float bv2 = sel[0]; int bi = lane * 4;
      #pragma unroll
      for (int j = 1; j < 4; ++j)
        if (sel[j] > bv2) { bv2 = sel[j]; bi = lane * 4 + j; }
      #pragma unroll
      for (int s = 1; s < 64; s <<= 1) {
        float ov = __shfl_xor(bv2, s);
        int   oi = __shfl_xor(bi, s);
        if (ov > bv2 || (ov == bv2 && oi < bi)) { bv2 = ov; bi = oi; }
      }
      if (lane == 0) {
        out_w[(size_t)gtok * TOPK + it]   = Sc[m][bi] * 2.5f;
        out_idx[(size_t)gtok * TOPK + it] = (float)bi;
        atomicAdd(&hist[bi], 1);
      }
      if ((bi >> 2) == lane) sel[bi & 3] = -INFINITY;
    }
  }

  __syncthreads();
  for (int b = tid; b < NEXP; b += NTHREADS)
    if (hist[b]) atomicAdd(&out_load[b], (float)hist[b]);
}

extern "C" void kernel_launch(void* const* d_in, const int* in_sizes, int n_in,
                              void* d_out, int out_size, void* d_ws, size_t ws_size,
                              hipStream_t stream) {
  const float* x    = (const float*)d_in[0];
  const float* w    = (const float*)d_in[1];
  const float* bias = (const float*)d_in[2];
  float* out_w    = (float*)d_out;
  float* out_idx  = out_w + (size_t)T_TOKENS * TOPK;
  float* out_load = out_idx + (size_t)T_TOKENS * TOPK;
  unsigned short* wfrag = (unsigned short*)d_ws;   // 1 MB fragment-ordered fp16 w

  hipMemsetAsync(out_load, 0, NEXP * sizeof(float), stream);
  prep_w<<<256, 256, 0, stream>>>(w, wfrag);
  gate_kernel<<<T_TOKENS / BM, NTHREADS, 0, stream>>>(
      x, wfrag, bias, out_w, out_idx, out_load);
}